// Round 9
// baseline (85.979 us; speedup 1.0000x reference)
//
#include <hip/hip_runtime.h>

#define HWN 9216   // 96*96
#define SCALE 0.1767766952966369f

static __device__ __forceinline__ float rcp_fast(float x) {
  return __builtin_amdgcn_rcpf(x);
}
static __device__ __forceinline__ float rl_f(float x, int l) {
  return __int_as_float(__builtin_amdgcn_readlane(__float_as_int(x), l));
}
template <int C>
static __device__ __forceinline__ float dpps(float x) {  // sum step (0-fill)
  return x + __int_as_float(__builtin_amdgcn_update_dpp(
                 0, __float_as_int(x), C, 0xf, 0xf, true));
}
static __device__ __forceinline__ float wave_sum63(float x) {
  x = dpps<0x111>(x); x = dpps<0x112>(x); x = dpps<0x114>(x);
  x = dpps<0x118>(x); x = dpps<0x142>(x); x = dpps<0x143>(x);
  return x;  // lane 63 holds the 64-lane total
}

// ---------------- Kernel 0: weight prep ----------------
// w_vpI[r][2c+0] = sum_{d<32} w_v[r][d]    * w_proj[d][c]      (head-0 half)
// w_vpI[r][2c+1] = sum_{d<32} w_v[r][d+32] * w_proj[d+32][c]   (head-1 half)
extern "C" __global__ void __launch_bounds__(256) prep_kernel(
    const float* __restrict__ w_v, const float* __restrict__ w_proj,
    float* __restrict__ w_vpI) {
  const int idx = blockIdx.x * 256 + threadIdx.x;  // 16 blocks -> 4096
  const int r = idx >> 6, c = idx & 63;
  float s0 = 0.f, s1 = 0.f;
#pragma unroll 8
  for (int d = 0; d < 32; ++d) {
    s0 += w_v[r * 64 + d] * w_proj[d * 64 + c];
    s1 += w_v[r * 64 + 32 + d] * w_proj[(32 + d) * 64 + c];
  }
  w_vpI[r * 128 + 2 * c] = s0;
  w_vpI[r * 128 + 2 * c + 1] = s1;
}

// ---------------- Kernel 1: QKV' projection (LDS-staged) ----------------
// Grid 1152 = 288 px-blocks x 4 col-blocks. qkv row = 256 floats/pixel:
// [ q*SCALE (64) | k (64) | vI (128: v0',v1' interleaved per channel) ]
extern "C" __global__ void __launch_bounds__(256) qkv_proj_kernel(
    const float* __restrict__ x, const float* __restrict__ w_qk,
    const float* __restrict__ w_vpI, float* __restrict__ qkv) {
  __shared__ __align__(16) float A[64 * 64];   // [d][px]
  __shared__ __align__(16) float Wl[64 * 64];  // [d][c]
  const int t = threadIdx.x;
  const int bid = blockIdx.x;
  const int cb = bid & 3;
  const int pxblk = bid >> 2;
  const int b = (pxblk >= 144) ? 1 : 0;
  const int p0 = (pxblk - b * 144) * 64;
  const float* xb = x + b * (64 * HWN) + p0;
  const float* wsrc = ((cb < 2) ? w_qk : w_vpI) + (cb & 1) * 64;
#pragma unroll
  for (int rep = 0; rep < 16; ++rep) {
    const int idx = rep * 256 + t;
    A[idx] = xb[(idx >> 6) * HWN + (idx & 63)];
    Wl[idx] = wsrc[(idx >> 6) * 128 + (idx & 63)];
  }
  __syncthreads();
  const int pxg = t >> 4, cg = t & 15;
  float acc[4][4];
#pragma unroll
  for (int p = 0; p < 4; ++p)
#pragma unroll
    for (int c = 0; c < 4; ++c) acc[p][c] = 0.f;
#pragma unroll 8
  for (int d = 0; d < 64; ++d) {
    const float4 av = *(const float4*)&A[d * 64 + pxg * 4];
    const float4 wv = *(const float4*)&Wl[d * 64 + cg * 4];
    const float aa[4] = {av.x, av.y, av.z, av.w};
    const float ww[4] = {wv.x, wv.y, wv.z, wv.w};
#pragma unroll
    for (int p = 0; p < 4; ++p)
#pragma unroll
      for (int c = 0; c < 4; ++c) acc[p][c] += aa[p] * ww[c];
  }
  const float sc = (cb == 0) ? SCALE : 1.f;
  const int pixbase = b * HWN + p0 + pxg * 4;
#pragma unroll
  for (int p = 0; p < 4; ++p) {
    *(float4*)&qkv[(pixbase + p) * 256 + cb * 64 + cg * 4] =
        make_float4(acc[p][0] * sc, acc[p][1] * sc, acc[p][2] * sc,
                    acc[p][3] * sc);
  }
}

// ---------------- Kernel 2: fused attention ----------------
// WG = 512 thr = 8 waves; 4x4 pixel tile; 2 PIXELS PER WAVE (ILP).
// QK: lane = neighbor, k pairs via ds_read_b64, q uniform b128.
// PV: lane = out channel, v' b64 from global (L2), weights via readlane.
extern "C" __global__ void __launch_bounds__(512, 6) attn_fused_kernel(
    const float* __restrict__ qkv, const float* __restrict__ sims,
    const float* __restrict__ b_proj, float* __restrict__ out) {
  __shared__ __align__(16) float kT2[32 * 102 * 2];  // 26112 B [dpair][cell] f2
  __shared__ __align__(16) float qL[16 * 64];        // 4096 B
  __shared__ float simsL[100 * 9];                   // 3600 B  total 33808 B

  const int t = threadIdx.x;
  const int lane = t & 63;
  const int wvv = t >> 6;

  int wg = blockIdx.x;  // 1152 = 2 * 24 * 24
  const int bb = (wg >= 576) ? 1 : 0;
  wg -= bb * 576;
  const int i0 = (wg / 24) * 4;
  const int j0 = (wg % 24) * 4;
  const int rstart0 = max(min(i0 - 3, 86), 0);  // 10 staged rows
  const int cstart0 = max(min(j0 - 3, 86), 0);  // 10 staged cols

  const float* qkvb = qkv + bb * (HWN * 256);
  const float bp = b_proj[lane];

  // ---- stage k pairs: 50 cell-pairs; lane covers (cell: hi bit, dpair) ----
  {
    const int dp = lane & 31, chalf = lane >> 5;
    for (int cp = wvv; cp < 50; cp += 8) {
      const int cell = 2 * cp + chalf;
      const int r = cell / 10, c = cell - r * 10;
      const int pix = (rstart0 + r) * 96 + (cstart0 + c);
      const float2 k2 = *(const float2*)(qkvb + pix * 256 + 64 + 2 * dp);
      *(float2*)&kT2[(dp * 102 + cell) * 2] = k2;
    }
  }
  // ---- stage q (pre-scaled): wave stages its 2 pixels ----
  {
#pragma unroll
    for (int h = 0; h < 2; ++h) {
      const int p = 2 * wvv + h;
      const int qi = i0 + (p >> 2), qj = j0 + (p & 3);
      qL[p * 64 + lane] = qkvb[(qi * 96 + qj) * 256 + lane];
    }
  }
  // ---- stage sims (+eps) ----
  {
    const int si = i0 >> 3, sj = j0 >> 3;
    const float* simsb = sims + bb * (HWN * 144);
    for (int el = t; el < 900; el += 512) {
      const int cell = el / 9;
      const int s = el - cell * 9;
      const int r = cell / 10, c = cell - cell / 10 * 10;
      const int pix = (rstart0 + r) * 96 + (cstart0 + c);
      const int sa = s / 3, sb2 = s - sa * 3;
      const int sr = min(max(si + sa - 1, 0), 11);
      const int sc = min(max(sj + sb2 - 1, 0), 11);
      simsL[cell * 9 + s] = simsb[pix * 144 + sr * 12 + sc] + 1e-12f;
    }
  }
  __syncthreads();

  // ---- per-wave: two pixels, fully interleaved ----
  const int nn = min(lane, 48);
  const int nr = nn / 7, nc = nn - nr * 7;

  int iP[2], jP[2], cellP[2];
  const float* vbaseP[2];
#pragma unroll
  for (int h = 0; h < 2; ++h) {
    const int p = 2 * wvv + h;
    const int i = i0 + (p >> 2), j = j0 + (p & 3);
    iP[h] = i; jP[h] = j;
    const int dr = max(min(i - 3, 89), 0) - rstart0;  // 0..3
    const int dc = max(min(j - 3, 89), 0) - cstart0;  // 0..3
    cellP[h] = (dr + nr) * 10 + (dc + nc);
    vbaseP[h] = qkvb + ((rstart0 + dr) * 96 + cstart0 + dc) * 256 + 128 + 2 * lane;
  }

  // QK: per px, 32 b64 k reads + uniform q b128
  float a0[2], a1[2];
#pragma unroll
  for (int h = 0; h < 2; ++h) { a0[h] = 0.f; a1[h] = 0.f; }
#pragma unroll
  for (int g = 0; g < 8; ++g) {
#pragma unroll
    for (int h = 0; h < 2; ++h) {
      const float4 q4 = *(const float4*)(&qL[(2 * wvv + h) * 64] + g * 4);
      const float2 ka = *(const float2*)&kT2[((2 * g) * 102 + cellP[h]) * 2];
      const float2 kb = *(const float2*)&kT2[((2 * g + 1) * 102 + cellP[h]) * 2];
      a0[h] += q4.x * ka.x + q4.y * ka.y + q4.z * kb.x + q4.w * kb.y;
    }
  }
#pragma unroll
  for (int g = 8; g < 16; ++g) {
#pragma unroll
    for (int h = 0; h < 2; ++h) {
      const float4 q4 = *(const float4*)(&qL[(2 * wvv + h) * 64] + g * 4);
      const float2 ka = *(const float2*)&kT2[((2 * g) * 102 + cellP[h]) * 2];
      const float2 kb = *(const float2*)&kT2[((2 * g + 1) * 102 + cellP[h]) * 2];
      a1[h] += q4.x * ka.x + q4.y * ka.y + q4.z * kb.x + q4.w * kb.y;
    }
  }
  // softmax without max-subtraction (logits O(+-7); f32 headroom)
  float e0[2], e1[2];
#pragma unroll
  for (int h = 0; h < 2; ++h) {
    e0[h] = (lane < 49) ? __expf(a0[h]) : 0.f;
    e1[h] = (lane < 49) ? __expf(a1[h]) : 0.f;
  }

  // Z_s per head per px; combine weights (chains interleaved 4-wide)
  float w0[2], w1[2];
#pragma unroll
  for (int h = 0; h < 2; ++h) { w0[h] = 0.f; w1[h] = 0.f; }
#pragma unroll
  for (int s = 0; s < 9; ++s) {
#pragma unroll
    for (int h = 0; h < 2; ++h) {
      const float tvs = simsL[cellP[h] * 9 + s];
      const float Z0 = rl_f(wave_sum63(tvs * e0[h]), 63);
      const float Z1 = rl_f(wave_sum63(tvs * e1[h]), 63);
      const int cc = (iP[h] - rstart0) * 10 + (jP[h] - cstart0);
      const float pis = simsL[cc * 9 + s];
      w0[h] += tvs * (pis * rcp_fast(Z0));
      w1[h] += tvs * (pis * rcp_fast(Z1));
    }
  }
#pragma unroll
  for (int h = 0; h < 2; ++h) { w0[h] *= e0[h]; w1[h] *= e1[h]; }

  // PV: lane = out channel; two independent global b64 streams
  float o0[2], o1[2], o2[2], o3[2];
#pragma unroll
  for (int h = 0; h < 2; ++h) {
    o0[h] = (h == 0) ? bp : bp;  // bias once per px output
    o1[h] = 0.f; o2[h] = 0.f; o3[h] = 0.f;
  }
#pragma unroll
  for (int n = 0; n < 49; ++n) {
    const int goff = ((n / 7) * 96 + (n % 7)) * 256;
#pragma unroll
    for (int h = 0; h < 2; ++h) {
      const float2 v2 = *(const float2*)(vbaseP[h] + goff);
      const float wa = rl_f(w0[h], n);
      const float wb = rl_f(w1[h], n);
      if (n & 1) { o2[h] += wa * v2.x; o3[h] += wb * v2.y; }
      else       { o0[h] += wa * v2.x; o1[h] += wb * v2.y; }
    }
  }
#pragma unroll
  for (int h = 0; h < 2; ++h) {
    out[(bb * 64 + lane) * HWN + iP[h] * 96 + jP[h]] =
        (o0[h] + o2[h]) + (o1[h] + o3[h]);
  }
}

extern "C" void kernel_launch(void* const* d_in, const int* in_sizes, int n_in,
                              void* d_out, int out_size, void* d_ws, size_t ws_size,
                              hipStream_t stream) {
  const float* x      = (const float*)d_in[0];
  const float* sims   = (const float*)d_in[1];
  const float* w_qk   = (const float*)d_in[2];
  const float* w_v    = (const float*)d_in[3];
  const float* w_proj = (const float*)d_in[4];
  const float* b_proj = (const float*)d_in[5];
  float* outp  = (float*)d_out;
  float* qkv   = (float*)d_ws;                 // 18432*256*4 = 18.9 MB
  float* w_vpI = qkv + (size_t)18432 * 256;    // 8192 floats

  prep_kernel<<<dim3(16), dim3(256), 0, stream>>>(w_v, w_proj, w_vpI);
  qkv_proj_kernel<<<dim3(1152), dim3(256), 0, stream>>>(x, w_qk, w_vpI, qkv);
  attn_fused_kernel<<<dim3(1152), dim3(512), 0, stream>>>(qkv, sims, b_proj,
                                                          outp);
}

// Round 10
// 63.068 us; speedup vs baseline: 1.3633x; 1.3633x over previous
//
#include <hip/hip_runtime.h>

#define HWN 9216   // 96*96
#define SCALE 0.1767766952966369f

static __device__ __forceinline__ float rcp_fast(float x) {
  return __builtin_amdgcn_rcpf(x);
}
static __device__ __forceinline__ float rl_f(float x, int l) {
  return __int_as_float(__builtin_amdgcn_readlane(__float_as_int(x), l));
}
template <int C>
static __device__ __forceinline__ float dpps(float x) {  // sum step (0-fill)
  return x + __int_as_float(__builtin_amdgcn_update_dpp(
                 0, __float_as_int(x), C, 0xf, 0xf, true));
}
static __device__ __forceinline__ float wave_sum63(float x) {
  x = dpps<0x111>(x); x = dpps<0x112>(x); x = dpps<0x114>(x);
  x = dpps<0x118>(x); x = dpps<0x142>(x); x = dpps<0x143>(x);
  return x;  // lane 63 holds the 64-lane total
}

// ---------------- Kernel 0: weight prep ----------------
// w_vpC[r][ 0..63 ] = sum_{d<32} w_v[r][d]    * w_proj[d][c]     (head-0 half)
// w_vpC[r][64..127] = sum_{d<32} w_v[r][d+32] * w_proj[d+32][c]  (head-1 half)
extern "C" __global__ void __launch_bounds__(256) prep_kernel(
    const float* __restrict__ w_v, const float* __restrict__ w_proj,
    float* __restrict__ w_vpC) {
  const int idx = blockIdx.x * 256 + threadIdx.x;  // 16 blocks -> 4096
  const int r = idx >> 6, c = idx & 63;
  float s0 = 0.f, s1 = 0.f;
#pragma unroll 8
  for (int d = 0; d < 32; ++d) {
    s0 += w_v[r * 64 + d] * w_proj[d * 64 + c];
    s1 += w_v[r * 64 + 32 + d] * w_proj[(32 + d) * 64 + c];
  }
  w_vpC[r * 128 + c] = s0;
  w_vpC[r * 128 + 64 + c] = s1;
}

// ---------------- Kernel 1: QKV' projection (LDS-staged) ----------------
// Grid 1152 = 288 px-blocks x 4 col-blocks. qkv row = 256 floats/pixel:
// [ q*SCALE (64) | k (64) | v0' (64) | v1' (64) ]
extern "C" __global__ void __launch_bounds__(256) qkv_proj_kernel(
    const float* __restrict__ x, const float* __restrict__ w_qk,
    const float* __restrict__ w_vpC, float* __restrict__ qkv) {
  __shared__ __align__(16) float A[64 * 64];   // [d][px]
  __shared__ __align__(16) float Wl[64 * 64];  // [d][c]
  const int t = threadIdx.x;
  const int bid = blockIdx.x;
  const int cb = bid & 3;
  const int pxblk = bid >> 2;
  const int b = (pxblk >= 144) ? 1 : 0;
  const int p0 = (pxblk - b * 144) * 64;
  const float* xb = x + b * (64 * HWN) + p0;
  const float* wsrc = ((cb < 2) ? w_qk : w_vpC) + (cb & 1) * 64;
#pragma unroll
  for (int rep = 0; rep < 16; ++rep) {
    const int idx = rep * 256 + t;
    A[idx] = xb[(idx >> 6) * HWN + (idx & 63)];
    Wl[idx] = wsrc[(idx >> 6) * 128 + (idx & 63)];
  }
  __syncthreads();
  const int pxg = t >> 4, cg = t & 15;
  float acc[4][4];
#pragma unroll
  for (int p = 0; p < 4; ++p)
#pragma unroll
    for (int c = 0; c < 4; ++c) acc[p][c] = 0.f;
#pragma unroll 8
  for (int d = 0; d < 64; ++d) {
    const float4 av = *(const float4*)&A[d * 64 + pxg * 4];
    const float4 wv = *(const float4*)&Wl[d * 64 + cg * 4];
    const float aa[4] = {av.x, av.y, av.z, av.w};
    const float ww[4] = {wv.x, wv.y, wv.z, wv.w};
#pragma unroll
    for (int p = 0; p < 4; ++p)
#pragma unroll
      for (int c = 0; c < 4; ++c) acc[p][c] += aa[p] * ww[c];
  }
  const float sc = (cb == 0) ? SCALE : 1.f;
  const int pixbase = b * HWN + p0 + pxg * 4;
#pragma unroll
  for (int p = 0; p < 4; ++p) {
    *(float4*)&qkv[(pixbase + p) * 256 + cb * 64 + cg * 4] =
        make_float4(acc[p][0] * sc, acc[p][1] * sc, acc[p][2] * sc,
                    acc[p][3] * sc);
  }
}

// ---------------- Kernel 2: fused attention, HEAD-SPLIT ----------------
// WG = 512 thr = 8 waves = 4 pixels (one row) x 2 heads. Wave = (px, head).
// QK: lane = neighbor, 32 kT b32 imm-offset reads (one head's dims).
// PV: lane = out channel, contiguous 256B v'_h global loads, w via readlane.
// Head partials combined through oP[] LDS.
extern "C" __global__ void __launch_bounds__(512, 8) attn_fused_kernel(
    const float* __restrict__ qkv, const float* __restrict__ sims,
    const float* __restrict__ b_proj, float* __restrict__ out) {
  __shared__ __align__(16) float kT[64 * 71];  // 18176 B [d][cell] pad 71
  __shared__ float simsL[70 * 9];              // 2520 B
  __shared__ __align__(16) float qL[4 * 64];   // 1024 B
  __shared__ __align__(16) float oP[4 * 64];   // 1024 B   total ~22.8 KB

  const int t = threadIdx.x;
  const int lane = t & 63;
  const int wvv = t >> 6;
  const int px = wvv >> 1;    // 0..3
  const int head = wvv & 1;   // 0..1

  int wg = blockIdx.x;  // 4608 = 2 * 96 * 24
  const int bb = (wg >= 2304) ? 1 : 0;
  wg -= bb * 2304;
  const int i0 = wg / 24;
  const int j0 = (wg % 24) * 4;
  const int rstart0 = max(min(i0 - 3, 89), 0);  // 7 staged rows
  const int cstart0 = max(min(j0 - 3, 86), 0);  // 10 staged cols

  const float* qkvb = qkv + bb * (HWN * 256);

  // ---- stage k transposed: 70 cells, wave-strided ----
  for (int cell = wvv; cell < 70; cell += 8) {
    const int r = cell / 10, c = cell - r * 10;
    const int pix = (rstart0 + r) * 96 + (cstart0 + c);
    kT[lane * 71 + cell] = qkvb[pix * 256 + 64 + lane];
  }
  // ---- stage q (pre-scaled): 4 pixels ----
  if (wvv < 4) {
    qL[wvv * 64 + lane] = qkvb[(i0 * 96 + j0 + wvv) * 256 + lane];
  }
  // ---- stage sims (+eps) ----
  {
    const int si = i0 >> 3, sj = j0 >> 3;
    const float* simsb = sims + bb * (HWN * 144);
    for (int el = t; el < 630; el += 512) {
      const int cell = el / 9;
      const int s = el - cell * 9;
      const int r = cell / 10, c = cell - cell / 10 * 10;
      const int pix = (rstart0 + r) * 96 + (cstart0 + c);
      const int sa = s / 3, sb2 = s - sa * 3;
      const int sr = min(max(si + sa - 1, 0), 11);
      const int sc = min(max(sj + sb2 - 1, 0), 11);
      simsL[cell * 9 + s] = simsb[pix * 144 + sr * 12 + sc] + 1e-12f;
    }
  }
  __syncthreads();

  // ---- per-wave: pixel (i0, j), one head; lane owns neighbor nn ----
  const int j = j0 + px;
  const int dc = max(min(j - 3, 89), 0) - cstart0;  // 0..3
  const int nn = min(lane, 48);
  const int nr = nn / 7, nc = nn - nr * 7;
  const int cell = nr * 10 + (dc + nc);

  // QK: 32 conflict-free b32 k-reads (imm offsets), q uniform b128
  const float* qp = &qL[px * 64 + head * 32];
  const float* kp = &kT[head * 32 * 71 + cell];
  float a = 0.f;
#pragma unroll
  for (int g = 0; g < 8; ++g) {
    const float4 q4 = *(const float4*)(qp + g * 4);
    a += q4.x * kp[(g * 4 + 0) * 71] + q4.y * kp[(g * 4 + 1) * 71] +
         q4.z * kp[(g * 4 + 2) * 71] + q4.w * kp[(g * 4 + 3) * 71];
  }
  // softmax without max-subtraction (logits are O(+-7); f32 has headroom)
  const float e = (lane < 49) ? __expf(a) : 0.f;

  // Z_s = sum_n (Pj+eps)*e ; combine weights (9 independent DPP chains)
  const int cellc = (i0 - rstart0) * 10 + (j - cstart0);
  float w = 0.f;
#pragma unroll
  for (int s = 0; s < 9; ++s) {
    const float tvs = simsL[cell * 9 + s];
    const float Z = rl_f(wave_sum63(tvs * e), 63);
    const float pis = simsL[cellc * 9 + s];
    w += tvs * (pis * rcp_fast(Z));
  }
  w *= e;  // wcomb[head][n = lane]

  // PV: lane = out channel; contiguous 256B v'_h loads; w via readlane
  const float* vbase =
      qkvb + ((rstart0)*96 + cstart0 + dc) * 256 + 128 + head * 64 + lane;
  float o0 = 0.f, o1 = 0.f;
#pragma unroll
  for (int n = 0; n < 49; ++n) {
    const int goff = ((n / 7) * 96 + (n % 7)) * 256;
    const float vn = vbase[goff];
    const float wn = rl_f(w, n);
    if (n & 1) o1 += wn * vn;
    else       o0 += wn * vn;
  }
  const float o = o0 + o1;

  // ---- combine heads through LDS ----
  if (head == 1) oP[px * 64 + lane] = o;
  __syncthreads();
  if (head == 0) {
    out[(bb * 64 + lane) * HWN + i0 * 96 + j] =
        o + oP[px * 64 + lane] + b_proj[lane];
  }
}

extern "C" void kernel_launch(void* const* d_in, const int* in_sizes, int n_in,
                              void* d_out, int out_size, void* d_ws, size_t ws_size,
                              hipStream_t stream) {
  const float* x      = (const float*)d_in[0];
  const float* sims   = (const float*)d_in[1];
  const float* w_qk   = (const float*)d_in[2];
  const float* w_v    = (const float*)d_in[3];
  const float* w_proj = (const float*)d_in[4];
  const float* b_proj = (const float*)d_in[5];
  float* outp  = (float*)d_out;
  float* qkv   = (float*)d_ws;                 // 18432*256*4 = 18.9 MB
  float* w_vpC = qkv + (size_t)18432 * 256;    // 8192 floats

  prep_kernel<<<dim3(16), dim3(256), 0, stream>>>(w_v, w_proj, w_vpC);
  qkv_proj_kernel<<<dim3(1152), dim3(256), 0, stream>>>(x, w_qk, w_vpC, qkv);
  attn_fused_kernel<<<dim3(4608), dim3(512), 0, stream>>>(qkv, sims, b_proj,
                                                          outp);
}